// Round 8
// baseline (128.027 us; speedup 1.0000x reference)
//
#include <hip/hip_runtime.h>
#include <hip/hip_bf16.h>
#include <cmath>

// Problem constants: V=100000, E=128, B=32, S=1024, N=16
#define NS_ROWS  32768u
#define NS_PAIRS (NS_ROWS * 17u)        // 557056 = 8704 blocks * 64 quads

typedef float f32x4 __attribute__((ext_vector_type(4)));

// Force a 16B global load into a named VGPR quad, issued without a wait.
// Separate volatile asms stay in program order; results stay live -> regalloc
// must hold all of them in flight (the compiler refuses to do this for C++
// loads: R3/R5/R6 all collapsed to VGPR<=32 serialized load->wait->dot chains).
#define GLOAD16(dst, base, imm)                                        \
    asm volatile("global_load_dwordx4 %0, %1, off offset:" #imm        \
                 : "=v"(dst) : "v"(base))

__device__ __forceinline__ float log_sigmoid_f(float x) {
    return fminf(x, 0.0f) - log1pf(__expf(-fabsf(x)));
}

__device__ __forceinline__ float dot4(const f32x4 a, const f32x4 b) {
    return a.x * b.x + a.y * b.y + a.z * b.z + a.w * b.w;
}

__global__ __launch_bounds__(256) void neg_sampling_kernel(
    const int*   __restrict__ sentence,   // [ROWS]
    const float* __restrict__ context,    // [ROWS, 128]
    const int*   __restrict__ neg,        // [ROWS, 16]
    const float* __restrict__ W,          // [V, 128]
    float*       __restrict__ out)        // scalar
{
    const int tid = threadIdx.x;
    const unsigned pair = (blockIdx.x << 6) | (unsigned)(tid >> 2);
    const int sub = tid & 3;

    const unsigned row = pair / 17u;
    const unsigned tgt = pair - row * 17u;

    const int idx = (tgt == 0u) ? sentence[row] : neg[(row << 4) + (tgt - 1u)];

    // lane sub covers byte offsets sub*16 + k*64 of each 512B row
    const float* wb = W       + ((size_t)idx << 7) + (sub << 2);
    const float* cb = context + ((size_t)row << 7) + (sub << 2);

    f32x4 w0, w1, w2, w3, w4, w5, w6, w7;
    f32x4 c0, c1, c2, c3, c4, c5, c6, c7;

    // Issue all 16 loads back-to-back; no intermediate waits.
    GLOAD16(w0, wb,   0);  GLOAD16(w1, wb,  64);
    GLOAD16(w2, wb, 128);  GLOAD16(w3, wb, 192);
    GLOAD16(w4, wb, 256);  GLOAD16(w5, wb, 320);
    GLOAD16(w6, wb, 384);  GLOAD16(w7, wb, 448);
    GLOAD16(c0, cb,   0);  GLOAD16(c1, cb,  64);
    GLOAD16(c2, cb, 128);  GLOAD16(c3, cb, 192);
    GLOAD16(c4, cb, 256);  GLOAD16(c5, cb, 320);
    GLOAD16(c6, cb, 384);  GLOAD16(c7, cb, 448);

    // Drain once, then fence so the register-only dots can't hoist above it.
    asm volatile("s_waitcnt vmcnt(0)" ::: "memory");
    __builtin_amdgcn_sched_barrier(0);

    float acc;
    acc  = dot4(w0, c0);
    acc += dot4(w1, c1);
    acc += dot4(w2, c2);
    acc += dot4(w3, c3);
    acc += dot4(w4, c4);
    acc += dot4(w5, c5);
    acc += dot4(w6, c6);
    acc += dot4(w7, c7);

    // quad butterfly -> full 128-dot in every lane of the quad
    acc += __shfl_xor(acc, 1, 64);
    acc += __shfl_xor(acc, 2, 64);

    float loss = (sub == 0) ? log_sigmoid_f((tgt == 0u) ? acc : -acc) : 0.0f;

    // wave butterfly -> 4-wave block reduce -> one atomic per block
#pragma unroll
    for (int m = 32; m >= 1; m >>= 1) loss += __shfl_xor(loss, m, 64);

    __shared__ float wsum[4];
    const int wave = tid >> 6, lane = tid & 63;
    if (lane == 0) wsum[wave] = loss;
    __syncthreads();
    if (tid == 0) {
        atomicAdd(out, -(wsum[0] + wsum[1] + wsum[2] + wsum[3]));
    }
}

extern "C" void kernel_launch(void* const* d_in, const int* in_sizes, int n_in,
                              void* d_out, int out_size, void* d_ws, size_t ws_size,
                              hipStream_t stream) {
    const int*   sentence = (const int*)d_in[0];
    const float* context  = (const float*)d_in[1];
    const int*   neg      = (const int*)d_in[2];
    const float* W        = (const float*)d_in[3];
    float*       out      = (float*)d_out;

    hipMemsetAsync(out, 0, sizeof(float), stream);

    const int blocks = NS_PAIRS / 64;   // 8704, exact
    neg_sampling_kernel<<<blocks, 256, 0, stream>>>(sentence, context, neg, W, out);
}

// Round 9
// 62.380 us; speedup vs baseline: 2.0524x; 2.0524x over previous
//
#include <hip/hip_runtime.h>
#include <hip/hip_bf16.h>
#include <cmath>

// Problem constants: V=100000, E=128, B=32, S=1024, N=16
#define NS_ROWS   32768u
#define NS_PAIRS  (NS_ROWS * 17u)        // 557056 = 69632 half-waves * 8 pairs
#define NS_BLOCKS 8704                   // 256 thr = 8 half-waves; 8704*8*8 = 557056

__device__ __forceinline__ float log_sigmoid_f(float x) {
    return fminf(x, 0.0f) - log1pf(__expf(-fabsf(x)));
}

// One HALF-WAVE (32 lanes) per pair-step: a full 512B W row in ONE coalesced
// load instruction (32 lanes x float4). Per-thread dependency chain is just
// idx -> (W row || ctx row) -> dot4 -> 5-shuffle butterfly: depth the compiler
// cannot serialize further. Concurrency comes from occupancy (no LDS staging,
// no block barrier in the hot path, low VGPR -> 32 waves/CU).
__global__ __launch_bounds__(256) void ns_main_kernel(
    const int*   __restrict__ sentence,   // [ROWS]
    const float* __restrict__ context,    // [ROWS, 128]
    const int*   __restrict__ neg,        // [ROWS, 16]
    const float* __restrict__ W,          // [V, 128]
    float*       __restrict__ partial)    // [NS_BLOCKS]
{
    const int tid = threadIdx.x;
    const int l   = tid & 31;                         // lane within half-wave
    const unsigned g = blockIdx.x * 8u + (unsigned)(tid >> 5);  // half-wave id
    const unsigned p0 = g * 8u;                       // first of 8 consecutive pairs

    // prefetch idx for i=0
    unsigned r0 = p0 / 17u, t0 = p0 - r0 * 17u;
    int idx = (t0 == 0u) ? sentence[r0] : neg[(r0 << 4) + (t0 - 1u)];

    float loss = 0.0f;
#pragma unroll
    for (int i = 0; i < 8; ++i) {
        const unsigned p    = p0 + (unsigned)i;
        const unsigned prow = p / 17u;
        const unsigned ptgt = p - prow * 17u;
        const int cur = idx;

        // prefetch next pair's index (breaks the gather dependency chain)
        if (i < 7) {
            const unsigned pn = p + 1u;
            const unsigned nr = pn / 17u, nt = pn - nr * 17u;
            idx = (nt == 0u) ? sentence[nr] : neg[(nr << 4) + (nt - 1u)];
        }

        // full W row in one coalesced instruction; ctx row L1/reg-hot
        const float4 wv = *reinterpret_cast<const float4*>(W + ((size_t)cur << 7) + (l << 2));
        const float4 cv = *reinterpret_cast<const float4*>(context + ((size_t)prow << 7) + (l << 2));
        float acc = wv.x * cv.x + wv.y * cv.y + wv.z * cv.z + wv.w * cv.w;

        // 5-step butterfly within the half-wave -> all 32 lanes hold the dot
        acc += __shfl_xor(acc, 1,  64);
        acc += __shfl_xor(acc, 2,  64);
        acc += __shfl_xor(acc, 4,  64);
        acc += __shfl_xor(acc, 8,  64);
        acc += __shfl_xor(acc, 16, 64);

        // uniform across the half-wave (no divergence): accumulate on all lanes
        loss += log_sigmoid_f((ptgt == 0u) ? acc : -acc);
    }
    loss *= (1.0f / 32.0f);               // each half-wave lane counted it 32x

    // wave total = half-wave A + half-wave B, uniform across the wave
    loss = loss * 32.0f;                  // undo: keep exact per-pair sums
    loss = ((l == 0) ? loss : 0.0f);      // one lane per half-wave contributes
    loss += __shfl_xor(loss, 32, 64);
#pragma unroll
    for (int m = 16; m >= 1; m >>= 1) loss += __shfl_xor(loss, m, 64);

    __shared__ float wsum[4];
    const int wave = tid >> 6, lane = tid & 63;
    if (lane == 0) wsum[wave] = loss;
    __syncthreads();
    if (tid == 0) partial[blockIdx.x] = wsum[0] + wsum[1] + wsum[2] + wsum[3];
}

// Tiny second pass: sum 8704 partials, negate, write scalar out.
__global__ __launch_bounds__(1024) void ns_reduce_kernel(
    const float* __restrict__ partial, float* __restrict__ out)
{
    const int tid = threadIdx.x;
    float s = 0.0f;
    for (int i = tid; i < NS_BLOCKS; i += 1024) s += partial[i];
#pragma unroll
    for (int m = 32; m >= 1; m >>= 1) s += __shfl_xor(s, m, 64);

    __shared__ float wsum[16];
    const int wave = tid >> 6, lane = tid & 63;
    if (lane == 0) wsum[wave] = s;
    __syncthreads();
    if (tid == 0) {
        float t = 0.0f;
#pragma unroll
        for (int i = 0; i < 16; ++i) t += wsum[i];
        out[0] = -t;
    }
}

extern "C" void kernel_launch(void* const* d_in, const int* in_sizes, int n_in,
                              void* d_out, int out_size, void* d_ws, size_t ws_size,
                              hipStream_t stream) {
    const int*   sentence = (const int*)d_in[0];
    const float* context  = (const float*)d_in[1];
    const int*   neg      = (const int*)d_in[2];
    const float* W        = (const float*)d_in[3];
    float*       out      = (float*)d_out;
    float*       partial  = (float*)d_ws;            // 8704 floats = 34 KB

    ns_main_kernel<<<NS_BLOCKS, 256, 0, stream>>>(sentence, context, neg, W, partial);
    ns_reduce_kernel<<<1, 1024, 0, stream>>>(partial, out);
}

// Round 10
// 56.773 us; speedup vs baseline: 2.2550x; 1.0988x over previous
//
#include <hip/hip_runtime.h>
#include <hip/hip_bf16.h>
#include <cmath>

// Problem constants: V=100000, E=128, B=32, S=1024, N=16
#define NS_ROWS   32768u
#define NS_PAIRS  (NS_ROWS * 17u)       // 557056 = 8704 blocks * 64 pairs
#define NS_BLOCKS 8704

__device__ __forceinline__ float log_sigmoid_f(float x) {
    return fminf(x, 0.0f) - log1pf(__expf(-fabsf(x)));
}

__device__ __forceinline__ float dot4(const float4 a, const float4 b) {
    return a.x * b.x + a.y * b.y + a.z * b.z + a.w * b.w;
}

// 16 lanes per (row,target) pair. Lane m owns floats [8m, 8m+8) of both rows:
// 2 W float4 + 2 ctx float4, ALL independent -> fits the compiler's proven
// depth-2x2 issue window; no serial gather chain (R2/R6/R8 failure), and only
// 4 shuffles per pair amortized across the wave (R1/R9 failure). No LDS, no
// mid-kernel barrier; occupancy + wave count hide latency.
__global__ __launch_bounds__(1024) void ns_main_kernel(
    const int*   __restrict__ sentence,   // [ROWS]
    const float* __restrict__ context,    // [ROWS, 128]
    const int*   __restrict__ neg,        // [ROWS, 16]
    const float* __restrict__ W,          // [V, 128]
    float*       __restrict__ partial)    // [NS_BLOCKS]
{
    const int tid = threadIdx.x;
    const int m   = tid & 15;                                  // slice within pair
    const unsigned pair = (blockIdx.x << 6) | (unsigned)(tid >> 4);

    const unsigned row = pair / 17u;          // magic-mul
    const unsigned tgt = pair - row * 17u;

    // ctx loads first: independent of idx, issue immediately
    const float* cb = context + ((size_t)row << 7) + (m << 3);
    const float4 c0 = *reinterpret_cast<const float4*>(cb);
    const float4 c1 = *reinterpret_cast<const float4*>(cb + 4);

    const int idx = (tgt == 0u) ? sentence[row] : neg[(row << 4) + (tgt - 1u)];

    const float* wb = W + ((size_t)idx << 7) + (m << 3);
    const float4 w0 = *reinterpret_cast<const float4*>(wb);
    const float4 w1 = *reinterpret_cast<const float4*>(wb + 4);

    float acc = dot4(w0, c0) + dot4(w1, c1);

    // 4-step butterfly within the 16-lane group -> full 128-dot
    acc += __shfl_xor(acc, 1, 64);
    acc += __shfl_xor(acc, 2, 64);
    acc += __shfl_xor(acc, 4, 64);
    acc += __shfl_xor(acc, 8, 64);

    float loss = (m == 0) ? log_sigmoid_f((tgt == 0u) ? acc : -acc) : 0.0f;

    // full-wave butterfly (non-contributing lanes hold 0)
#pragma unroll
    for (int s = 32; s >= 1; s >>= 1) loss += __shfl_xor(loss, s, 64);

    __shared__ float wsum[16];
    const int wave = tid >> 6, lane = tid & 63;
    if (lane == 0) wsum[wave] = loss;
    __syncthreads();
    if (tid == 0) {
        float t = 0.0f;
#pragma unroll
        for (int i = 0; i < 16; ++i) t += wsum[i];
        partial[blockIdx.x] = t;
    }
}

// Second pass: sum 8704 partials, negate, write scalar.
__global__ __launch_bounds__(1024) void ns_reduce_kernel(
    const float* __restrict__ partial, float* __restrict__ out)
{
    const int tid = threadIdx.x;
    float s = 0.0f;
    for (int i = tid; i < NS_BLOCKS; i += 1024) s += partial[i];
#pragma unroll
    for (int m = 32; m >= 1; m >>= 1) s += __shfl_xor(s, m, 64);

    __shared__ float wsum[16];
    const int wave = tid >> 6, lane = tid & 63;
    if (lane == 0) wsum[wave] = s;
    __syncthreads();
    if (tid == 0) {
        float t = 0.0f;
#pragma unroll
        for (int i = 0; i < 16; ++i) t += wsum[i];
        out[0] = -t;
    }
}

extern "C" void kernel_launch(void* const* d_in, const int* in_sizes, int n_in,
                              void* d_out, int out_size, void* d_ws, size_t ws_size,
                              hipStream_t stream) {
    const int*   sentence = (const int*)d_in[0];
    const float* context  = (const float*)d_in[1];
    const int*   neg      = (const int*)d_in[2];
    const float* W        = (const float*)d_in[3];
    float*       out      = (float*)d_out;
    float*       partial  = (float*)d_ws;            // 8704 floats = 34 KB

    ns_main_kernel<<<NS_BLOCKS, 1024, 0, stream>>>(sentence, context, neg, W, partial);
    ns_reduce_kernel<<<1, 1024, 0, stream>>>(partial, out);
}